// Round 7
// baseline (620.566 us; speedup 1.0000x reference)
//
#include <hip/hip_runtime.h>

#define N_NODES 50000
#define N_EDGES 800000
#define N_EL    200000
#define CH      128
#define NT32    1563   // ceil(50000/32)

typedef __attribute__((ext_vector_type(8))) short bf16x8;
typedef __attribute__((ext_vector_type(4))) float f32x4;

__device__ __forceinline__ unsigned short f2bf(float f){
  unsigned int u = __float_as_uint(f);
  unsigned int r = (u + 0x7fff + ((u >> 16) & 1)) >> 16;
  return (unsigned short)r;
}
__device__ __forceinline__ float bflo(unsigned int v){ return __uint_as_float(v << 16); }
__device__ __forceinline__ float bfhi(unsigned int v){ return __uint_as_float(v & 0xffff0000u); }
__device__ __forceinline__ float bf2f(unsigned short u){ return __uint_as_float(((unsigned int)u) << 16); }

// ---------------- degree histogram --------------------------------------------
__global__ void hist_kernel(const int* __restrict__ ei, int* deg, int* cnt){
  int i = blockIdx.x*blockDim.x + threadIdx.x;
  if (i < N_EDGES){
    atomicAdd(&deg[ei[i]], 1);
    atomicAdd(&cnt[ei[N_EDGES + i]], 1);
  }
}

__global__ void dinv_kernel(const int* __restrict__ deg, float* __restrict__ dinv){
  int i = blockIdx.x*blockDim.x + threadIdx.x;
  if (i < N_NODES){
    int d = deg[i];
    dinv[i] = d > 0 ? rsqrtf((float)d) : 0.0f;
  }
}

// ---------------- hierarchical exclusive scan ---------------------------------
#define SCAN_NB 196   // ceil(50000/256)

__global__ void scan_bsum(const int* __restrict__ cnt, int* __restrict__ bsum){
  __shared__ int sh[256];
  int i = blockIdx.x*256 + threadIdx.x;
  sh[threadIdx.x] = (i < N_NODES) ? cnt[i] : 0;
  __syncthreads();
  for (int off = 128; off >= 1; off >>= 1){
    if ((int)threadIdx.x < off) sh[threadIdx.x] += sh[threadIdx.x + off];
    __syncthreads();
  }
  if (threadIdx.x == 0) bsum[blockIdx.x] = sh[0];
}

__global__ void scan_boff(const int* __restrict__ bsum, int* __restrict__ boff){
  __shared__ int sh[256];
  int t = threadIdx.x;
  int v = (t < SCAN_NB) ? bsum[t] : 0;
  sh[t] = v;
  __syncthreads();
  for (int off = 1; off < 256; off <<= 1){
    int tv = (t >= off) ? sh[t - off] : 0;
    __syncthreads();
    sh[t] += tv;
    __syncthreads();
  }
  if (t < SCAN_NB) boff[t] = sh[t] - v;
}

__global__ void scan_final(const int* __restrict__ cnt, const int* __restrict__ boff,
                           int* __restrict__ rowoff, int* __restrict__ cursor){
  __shared__ int sh[256];
  int t = threadIdx.x;
  int i = blockIdx.x*256 + t;
  int v = (i < N_NODES) ? cnt[i] : 0;
  sh[t] = v;
  __syncthreads();
  for (int off = 1; off < 256; off <<= 1){
    int tv = (t >= off) ? sh[t - off] : 0;
    __syncthreads();
    sh[t] += tv;
    __syncthreads();
  }
  int o = boff[blockIdx.x] + sh[t] - v;
  if (i < N_NODES){ rowoff[i] = o; cursor[i] = o; }
  if (i == N_NODES - 1) rowoff[N_NODES] = N_EDGES;
}

__global__ void scatter_kernel(const int* __restrict__ ei, const float* __restrict__ dinv,
                               int* cursor, int* __restrict__ csr_src,
                               float* __restrict__ csr_norm){
  int i = blockIdx.x*blockDim.x + threadIdx.x;
  if (i < N_EDGES){
    int s = ei[i];
    int d = ei[N_EDGES + i];
    int pos = atomicAdd(&cursor[d], 1);
    csr_src[pos]  = s;
    csr_norm[pos] = -(dinv[s] * dinv[d]);
  }
}

// ---------------- converts ----------------------------------------------------
// xH[node][0..127]=bf16(x row), [128..255]=bf16(H row)
__global__ void cvt_xH(const float* __restrict__ x, const float* __restrict__ H,
                       unsigned short* __restrict__ xH){
  const int Q = (N_NODES*CH)/4;
  int i = blockIdx.x*blockDim.x + threadIdx.x;
  if (i >= 2*Q) return;
  const float* src = (i < Q) ? x : H;
  int off = (i < Q) ? i : i - Q;
  float4 v = ((const float4*)src)[off];
  int node = off >> 5, cg = off & 31;
  uint2 o;
  o.x = (unsigned int)f2bf(v.x) | ((unsigned int)f2bf(v.y) << 16);
  o.y = (unsigned int)f2bf(v.z) | ((unsigned int)f2bf(v.w) << 16);
  *(uint2*)(xH + (size_t)node*256 + ((i < Q) ? 0 : 128) + cg*4) = o;
}

// wtg[m][col][k]: m=0..11 -> gate g=m>>2, t=m&3 in {Wx0,Wx1,Wh0,Wh1}[g] (g=2,t>=2 zero)
//                 m=12,13 -> Wh0[2], Wh1[2] (for the final GEMM)
__global__ void cvt_w(const float* __restrict__ Wx0, const float* __restrict__ Wx1,
                      const float* __restrict__ Wh0, const float* __restrict__ Wh1,
                      unsigned short* __restrict__ wtg){
  int i = blockIdx.x*blockDim.x + threadIdx.x;
  if (i >= 14*16384) return;
  int m = i >> 14;
  int r = i & 16383;
  int col = r >> 7, k = r & 127;
  float v;
  if (m < 12){
    int g = m >> 2, t = m & 3;
    int so = g*16384 + k*128 + col;
    if (t == 0)      v = Wx0[so];
    else if (t == 1) v = Wx1[so];
    else if (t == 2) v = (g < 2) ? Wh0[so] : 0.f;
    else             v = (g < 2) ? Wh1[so] : 0.f;
  } else {
    int so = 2*16384 + k*128 + col;
    v = (m == 12) ? Wh0[so] : Wh1[so];
  }
  wtg[(size_t)m*16384 + col*128 + k] = f2bf(v);
}

// ---------------- prop over interleaved x|H (one 512B read per edge) ----------
__global__ void prop_x2(const int* __restrict__ rowoff, const int* __restrict__ csr_src,
                        const float* __restrict__ csr_norm,
                        const unsigned short* __restrict__ xH,
                        unsigned short* __restrict__ px, unsigned short* __restrict__ pH){
  int node = blockIdx.x*4 + ((int)threadIdx.x >> 6);
  if (node >= N_NODES) return;
  int lane = threadIdx.x & 63;
  int half = lane >> 5, il = lane & 31;
  const unsigned short* base = xH + half*128 + il*4;
  int beg = rowoff[node], end = rowoff[node+1];
  float a0 = 0.f, a1 = 0.f, a2 = 0.f, a3 = 0.f;
  int k = beg;
  for (; k + 8 <= end; k += 8){
    int s[8]; float wn[8]; uint2 v[8];
    #pragma unroll
    for (int u = 0; u < 8; ++u){ s[u] = csr_src[k+u]; wn[u] = csr_norm[k+u]; }
    #pragma unroll
    for (int u = 0; u < 8; ++u) v[u] = *(const uint2*)(base + (size_t)s[u]*256);
    #pragma unroll
    for (int u = 0; u < 8; ++u){
      a0 += wn[u]*bflo(v[u].x); a1 += wn[u]*bfhi(v[u].x);
      a2 += wn[u]*bflo(v[u].y); a3 += wn[u]*bfhi(v[u].y);
    }
  }
  for (; k < end; ++k){
    int s = csr_src[k];
    float w = csr_norm[k];
    uint2 v = *(const uint2*)(base + (size_t)s*256);
    a0 += w*bflo(v.x); a1 += w*bfhi(v.x);
    a2 += w*bflo(v.y); a3 += w*bfhi(v.y);
  }
  uint2 o;
  o.x = (unsigned int)f2bf(a0) | ((unsigned int)f2bf(a1) << 16);
  o.y = (unsigned int)f2bf(a2) | ((unsigned int)f2bf(a3) << 16);
  unsigned short* O = (half ? pH : px) + (size_t)node*CH + il*4;
  *(uint2*)O = o;
}

// ---------------- prop of one matrix (stride-128 input) -----------------------
__global__ void prop_one(const int* __restrict__ rowoff, const int* __restrict__ csr_src,
                         const float* __restrict__ csr_norm,
                         const unsigned short* __restrict__ V,
                         unsigned short* __restrict__ O){
  int node = blockIdx.x*4 + ((int)threadIdx.x >> 6);
  if (node >= N_NODES) return;
  int lane = threadIdx.x & 63;
  const unsigned short* base = V + lane*2;
  int beg = rowoff[node], end = rowoff[node+1];
  float a0 = 0.f, a1 = 0.f;
  int k = beg;
  for (; k + 8 <= end; k += 8){
    int s[8]; float wn[8]; unsigned int v[8];
    #pragma unroll
    for (int u = 0; u < 8; ++u){ s[u] = csr_src[k+u]; wn[u] = csr_norm[k+u]; }
    #pragma unroll
    for (int u = 0; u < 8; ++u) v[u] = *(const unsigned int*)(base + (size_t)s[u]*CH);
    #pragma unroll
    for (int u = 0; u < 8; ++u){
      a0 += wn[u]*bflo(v[u]); a1 += wn[u]*bfhi(v[u]);
    }
  }
  for (; k < end; ++k){
    int s = csr_src[k];
    float w = csr_norm[k];
    unsigned int v = *(const unsigned int*)(base + (size_t)s*CH);
    a0 += w*bflo(v); a1 += w*bfhi(v);
  }
  *(unsigned int*)(O + (size_t)node*CH + lane*2) =
      (unsigned int)f2bf(a0) | ((unsigned int)f2bf(a1) << 16);
}

// ---------------- gate GEMM, split by (gate, col-half) across blocks ----------
// grid (nb, 6): flavor = y>>1 (0=Z 1=R 2=P), colhalf = y&1.
// block 256 = 4 waves, wave owns 16 cols; B stationary: 16 frags = 64 VGPR.
// rows/tile = 32 (2 row-groups). All pointers restrict -> pipelinable.
__launch_bounds__(256, 4)
__global__ void mfma_gsplit(const unsigned short* __restrict__ xH,
                            const unsigned short* __restrict__ px,
                            const unsigned short* __restrict__ pH,
                            const unsigned short* __restrict__ wtg,
                            const float* __restrict__ bx, const float* __restrict__ bh,
                            unsigned short* __restrict__ zb,
                            unsigned short* __restrict__ hrb,
                            float* __restrict__ pre2){
  const int flavor  = blockIdx.y >> 1;
  const int colhalf = blockIdx.y & 1;
  int lane = threadIdx.x & 63;
  int w    = threadIdx.x >> 6;
  int lr   = lane & 15;
  int kq   = lane >> 4;
  int mycol = colhalf*64 + w*16 + lr;

  const unsigned short* Am[4] = {xH, px, xH + 128, pH};
  const int strA[4] = {256, 128, 256, 128};

  bf16x8 BF[16];
  #pragma unroll
  for (int t = 0; t < 4; ++t)
    #pragma unroll
    for (int q = 0; q < 4; ++q)
      BF[t*4+q] = *(const bf16x8*)(wtg + (size_t)(flavor*4 + t)*16384
                                   + (size_t)mycol*CH + q*32 + kq*8);

  float bs = (flavor == 0) ? bx[mycol] + bh[mycol]
           : (flavor == 1) ? bx[128 + mycol] + bh[128 + mycol]
                           : bx[256 + mycol];

  for (int tile = blockIdx.x; tile < NT32; tile += gridDim.x){
    int r0 = tile * 32;
    int rA0 = min(r0 + lr,      N_NODES - 1);
    int rA1 = min(r0 + 16 + lr, N_NODES - 1);
    f32x4 acc0 = (f32x4){0.f,0.f,0.f,0.f};
    f32x4 acc1 = (f32x4){0.f,0.f,0.f,0.f};
    #pragma unroll
    for (int t = 0; t < 4; ++t){
      const unsigned short* Ap = Am[t];
      const int st = strA[t];
      #pragma unroll
      for (int q = 0; q < 4; ++q){
        bf16x8 a0 = *(const bf16x8*)(Ap + (size_t)rA0*st + q*32 + kq*8);
        bf16x8 a1 = *(const bf16x8*)(Ap + (size_t)rA1*st + q*32 + kq*8);
        acc0 = __builtin_amdgcn_mfma_f32_16x16x32_bf16(a0, BF[t*4+q], acc0, 0, 0, 0);
        acc1 = __builtin_amdgcn_mfma_f32_16x16x32_bf16(a1, BF[t*4+q], acc1, 0, 0, 0);
      }
    }
    #pragma unroll
    for (int rg = 0; rg < 2; ++rg){
      const f32x4& ac = rg ? acc1 : acc0;
      #pragma unroll
      for (int j = 0; j < 4; ++j){
        int row = r0 + rg*16 + kq*4 + j;
        if (row >= N_NODES) continue;
        size_t o = (size_t)row*CH + mycol;
        float v = ac[j] + bs;
        if (flavor == 0){
          zb[o] = f2bf(1.0f/(1.0f + __expf(-v)));
        } else if (flavor == 1){
          float h = bf2f(xH[(size_t)row*256 + 128 + mycol]);
          hrb[o] = f2bf(h * (1.0f/(1.0f + __expf(-v))));
        } else {
          pre2[o] = v;
        }
      }
    }
  }
}

// ---------------- final: gate2 h-part + GRU epilogue --------------------------
// grid (nb, 2): colhalf. block 256 = 4 waves x 16 cols. B: 8 frags = 32 VGPR.
__launch_bounds__(256, 4)
__global__ void mfma_fsplit(const unsigned short* __restrict__ hr,
                            const unsigned short* __restrict__ phr,
                            const unsigned short* __restrict__ wtg,
                            const float* __restrict__ bh,
                            const float* __restrict__ Hp, const float* __restrict__ pre2,
                            const unsigned short* __restrict__ zb,
                            float* __restrict__ hidden,
                            unsigned short* __restrict__ relu_b){
  const int colhalf = blockIdx.y;
  int lane = threadIdx.x & 63;
  int w    = threadIdx.x >> 6;
  int lr   = lane & 15;
  int kq   = lane >> 4;
  int mycol = colhalf*64 + w*16 + lr;

  const unsigned short* Am[2] = {hr, phr};

  bf16x8 BF[8];
  #pragma unroll
  for (int t = 0; t < 2; ++t)
    #pragma unroll
    for (int q = 0; q < 4; ++q)
      BF[t*4+q] = *(const bf16x8*)(wtg + (size_t)(12 + t)*16384
                                   + (size_t)mycol*CH + q*32 + kq*8);

  float bs = bh[256 + mycol];

  for (int tile = blockIdx.x; tile < NT32; tile += gridDim.x){
    int r0 = tile * 32;
    int rA0 = min(r0 + lr,      N_NODES - 1);
    int rA1 = min(r0 + 16 + lr, N_NODES - 1);
    f32x4 acc0 = (f32x4){0.f,0.f,0.f,0.f};
    f32x4 acc1 = (f32x4){0.f,0.f,0.f,0.f};
    #pragma unroll
    for (int t = 0; t < 2; ++t){
      const unsigned short* Ap = Am[t];
      #pragma unroll
      for (int q = 0; q < 4; ++q){
        bf16x8 a0 = *(const bf16x8*)(Ap + (size_t)rA0*CH + q*32 + kq*8);
        bf16x8 a1 = *(const bf16x8*)(Ap + (size_t)rA1*CH + q*32 + kq*8);
        acc0 = __builtin_amdgcn_mfma_f32_16x16x32_bf16(a0, BF[t*4+q], acc0, 0, 0, 0);
        acc1 = __builtin_amdgcn_mfma_f32_16x16x32_bf16(a1, BF[t*4+q], acc1, 0, 0, 0);
      }
    }
    #pragma unroll
    for (int rg = 0; rg < 2; ++rg){
      const f32x4& ac = rg ? acc1 : acc0;
      #pragma unroll
      for (int j = 0; j < 4; ++j){
        int row = r0 + rg*16 + kq*4 + j;
        if (row >= N_NODES) continue;
        size_t o = (size_t)row*CH + mycol;
        float ht = tanhf(ac[j] + bs + pre2[o]);
        float z  = bf2f(zb[o]);
        float h  = z*Hp[o] + (1.0f - z)*ht;
        hidden[o] = h;
        relu_b[o] = f2bf(fmaxf(h, 0.0f));
      }
    }
  }
}

// ---------------- link-pred scores: 16-lane group per pair, bf16 rows ---------
__global__ void scores_bf16(const int* __restrict__ eli, const unsigned short* __restrict__ hr,
                            const float* __restrict__ pw, const float* __restrict__ pb,
                            float* __restrict__ out){
  __shared__ float sw[CH];
  int t = threadIdx.x;
  if (t < CH) sw[t] = pw[2*t] + pw[2*t + 1];
  __syncthreads();
  int pair = blockIdx.x*16 + (t >> 4);
  if (pair >= N_EL) return;
  int il = t & 15;
  int a = eli[pair];
  int b = eli[N_EL + pair];
  bf16x8 va = *(const bf16x8*)(hr + (size_t)a*CH + il*8);
  bf16x8 vb = *(const bf16x8*)(hr + (size_t)b*CH + il*8);
  float s = 0.f;
  #pragma unroll
  for (int j = 0; j < 8; ++j){
    s += bf2f((unsigned short)va[j]) * bf2f((unsigned short)vb[j]) * sw[il*8 + j];
  }
  s += __shfl_xor(s, 1, 64);
  s += __shfl_xor(s, 2, 64);
  s += __shfl_xor(s, 4, 64);
  s += __shfl_xor(s, 8, 64);
  if (il == 0) out[pair] = s + pb[0] + pb[1];
}

extern "C" void kernel_launch(void* const* d_in, const int* in_sizes, int n_in,
                              void* d_out, int out_size, void* d_ws, size_t ws_size,
                              hipStream_t stream) {
  const float* x   = (const float*)d_in[0];
  const int*   ei  = (const int*)d_in[1];
  const int*   eli = (const int*)d_in[2];
  const float* H   = (const float*)d_in[3];
  const float* Wx0 = (const float*)d_in[4];
  const float* Wx1 = (const float*)d_in[5];
  const float* bx  = (const float*)d_in[6];
  const float* Wh0 = (const float*)d_in[7];
  const float* Wh1 = (const float*)d_in[8];
  const float* bh  = (const float*)d_in[9];
  const float* pw  = (const float*)d_in[10];
  const float* pb  = (const float*)d_in[11];
  float* out    = (float*)d_out;
  float* scores = out;
  float* hidden = out + N_EL;

  char* w = (char*)d_ws;
  auto alloc = [&](size_t b){ void* p = (void*)w; w += (b + 255) & ~(size_t)255; return p; };
  int*   deg      = (int*)  alloc((size_t)N_NODES*4);
  int*   cnt      = (int*)  alloc((size_t)N_NODES*4);
  float* dinv     = (float*)alloc((size_t)N_NODES*4);
  int*   rowoff   = (int*)  alloc((size_t)(N_NODES+1)*4);
  int*   cursor   = (int*)  alloc((size_t)N_NODES*4);
  int*   bsum     = (int*)  alloc((size_t)SCAN_NB*4);
  int*   boff     = (int*)  alloc((size_t)SCAN_NB*4);
  int*   csr_src  = (int*)  alloc((size_t)N_EDGES*4);
  float* csr_norm = (float*)alloc((size_t)N_EDGES*4);
  unsigned short* wtg = (unsigned short*)alloc((size_t)14*16384*2);
  unsigned short* xHb = (unsigned short*)alloc((size_t)N_NODES*256*2);  // x|H interleaved
  unsigned short* pxb = (unsigned short*)alloc((size_t)N_NODES*CH*2);
  unsigned short* pHb = (unsigned short*)alloc((size_t)N_NODES*CH*2);
  unsigned short* zbb = (unsigned short*)alloc((size_t)N_NODES*CH*2);
  unsigned short* hrb = (unsigned short*)alloc((size_t)N_NODES*CH*2);
  float* pre2 = (float*)alloc((size_t)N_NODES*CH*4);
  unsigned short* pHRb   = pHb;   // pHb dead after mfma_gsplit
  unsigned short* relu_b = pxb;   // pxb dead after mfma_gsplit

  hipMemsetAsync(deg, 0, (size_t)N_NODES*4, stream);
  hipMemsetAsync(cnt, 0, (size_t)N_NODES*4, stream);

  hist_kernel<<<(N_EDGES+255)/256, 256, 0, stream>>>(ei, deg, cnt);
  dinv_kernel<<<(N_NODES+255)/256, 256, 0, stream>>>(deg, dinv);
  scan_bsum <<<SCAN_NB, 256, 0, stream>>>(cnt, bsum);
  scan_boff <<<1, 256, 0, stream>>>(bsum, boff);
  scan_final<<<SCAN_NB, 256, 0, stream>>>(cnt, boff, rowoff, cursor);
  scatter_kernel<<<(N_EDGES+255)/256, 256, 0, stream>>>(ei, dinv, cursor, csr_src, csr_norm);

  cvt_xH<<<(((N_NODES*CH)/4)*2 + 255)/256, 256, 0, stream>>>(x, H, xHb);
  cvt_w <<<(14*16384 + 255)/256, 256, 0, stream>>>(Wx0, Wx1, Wh0, Wh1, wtg);

  prop_x2<<<(N_NODES+3)/4, 256, 0, stream>>>(rowoff, csr_src, csr_norm, xHb, pxb, pHb);

  // gates: Z (bf16 zbb), R -> HR (bf16 hrb), P2 (fp32 pre2); grid (96, 3x2)
  mfma_gsplit<<<dim3(96, 6), 256, 0, stream>>>(xHb, pxb, pHb, wtg, bx, bh,
                                               zbb, hrb, pre2);
  // pHR = prop(HR)
  prop_one<<<(N_NODES+3)/4, 256, 0, stream>>>(rowoff, csr_src, csr_norm, hrb, pHRb);
  // gate 2 h-part + GRU finalize: hidden (fp32, d_out) + relu (bf16)
  mfma_fsplit<<<dim3(192, 2), 256, 0, stream>>>(hrb, pHRb, wtg, bh,
                                                H, pre2, zbb, hidden, relu_b);

  scores_bf16<<<(N_EL+15)/16, 256, 0, stream>>>(eli, relu_b, pw, pb, scores);
}

// Round 8
// 596.199 us; speedup vs baseline: 1.0409x; 1.0409x over previous
//
#include <hip/hip_runtime.h>

#define N_NODES 50000
#define N_EDGES 800000
#define N_EL    200000
#define CH      128
#define NT64    782    // ceil(50000/64)

typedef __attribute__((ext_vector_type(8))) short bf16x8;
typedef __attribute__((ext_vector_type(4))) float f32x4;

__device__ __forceinline__ unsigned short f2bf(float f){
  unsigned int u = __float_as_uint(f);
  unsigned int r = (u + 0x7fff + ((u >> 16) & 1)) >> 16;
  return (unsigned short)r;
}
__device__ __forceinline__ float bflo(unsigned int v){ return __uint_as_float(v << 16); }
__device__ __forceinline__ float bfhi(unsigned int v){ return __uint_as_float(v & 0xffff0000u); }
__device__ __forceinline__ float bf2f(unsigned short u){ return __uint_as_float(((unsigned int)u) << 16); }

__device__ __forceinline__ void gload16(const void* g, void* l){
  __builtin_amdgcn_global_load_lds(
      (const __attribute__((address_space(1))) unsigned int*)g,
      (__attribute__((address_space(3))) unsigned int*)l, 16, 0, 0);
}

// ---------------- degree histogram --------------------------------------------
__global__ void hist_kernel(const int* __restrict__ ei, int* deg, int* cnt){
  int i = blockIdx.x*blockDim.x + threadIdx.x;
  if (i < N_EDGES){
    atomicAdd(&deg[ei[i]], 1);
    atomicAdd(&cnt[ei[N_EDGES + i]], 1);
  }
}

__global__ void dinv_kernel(const int* __restrict__ deg, float* __restrict__ dinv){
  int i = blockIdx.x*blockDim.x + threadIdx.x;
  if (i < N_NODES){
    int d = deg[i];
    dinv[i] = d > 0 ? rsqrtf((float)d) : 0.0f;
  }
}

// ---------------- hierarchical exclusive scan ---------------------------------
#define SCAN_NB 196   // ceil(50000/256)

__global__ void scan_bsum(const int* __restrict__ cnt, int* __restrict__ bsum){
  __shared__ int sh[256];
  int i = blockIdx.x*256 + threadIdx.x;
  sh[threadIdx.x] = (i < N_NODES) ? cnt[i] : 0;
  __syncthreads();
  for (int off = 128; off >= 1; off >>= 1){
    if ((int)threadIdx.x < off) sh[threadIdx.x] += sh[threadIdx.x + off];
    __syncthreads();
  }
  if (threadIdx.x == 0) bsum[blockIdx.x] = sh[0];
}

__global__ void scan_boff(const int* __restrict__ bsum, int* __restrict__ boff){
  __shared__ int sh[256];
  int t = threadIdx.x;
  int v = (t < SCAN_NB) ? bsum[t] : 0;
  sh[t] = v;
  __syncthreads();
  for (int off = 1; off < 256; off <<= 1){
    int tv = (t >= off) ? sh[t - off] : 0;
    __syncthreads();
    sh[t] += tv;
    __syncthreads();
  }
  if (t < SCAN_NB) boff[t] = sh[t] - v;
}

__global__ void scan_final(const int* __restrict__ cnt, const int* __restrict__ boff,
                           int* __restrict__ rowoff, int* __restrict__ cursor){
  __shared__ int sh[256];
  int t = threadIdx.x;
  int i = blockIdx.x*256 + t;
  int v = (i < N_NODES) ? cnt[i] : 0;
  sh[t] = v;
  __syncthreads();
  for (int off = 1; off < 256; off <<= 1){
    int tv = (t >= off) ? sh[t - off] : 0;
    __syncthreads();
    sh[t] += tv;
    __syncthreads();
  }
  int o = boff[blockIdx.x] + sh[t] - v;
  if (i < N_NODES){ rowoff[i] = o; cursor[i] = o; }
  if (i == N_NODES - 1) rowoff[N_NODES] = N_EDGES;
}

__global__ void scatter_kernel(const int* __restrict__ ei, const float* __restrict__ dinv,
                               int* cursor, int* __restrict__ csr_src,
                               float* __restrict__ csr_norm){
  int i = blockIdx.x*blockDim.x + threadIdx.x;
  if (i < N_EDGES){
    int s = ei[i];
    int d = ei[N_EDGES + i];
    int pos = atomicAdd(&cursor[d], 1);
    csr_src[pos]  = s;
    csr_norm[pos] = -(dinv[s] * dinv[d]);
  }
}

// ---------------- converts ----------------------------------------------------
// xH[node][0..127]=bf16(x row), [128..255]=bf16(H row)
__global__ void cvt_xH(const float* __restrict__ x, const float* __restrict__ H,
                       unsigned short* __restrict__ xH){
  const int Q = (N_NODES*CH)/4;
  int i = blockIdx.x*blockDim.x + threadIdx.x;
  if (i >= 2*Q) return;
  const float* src = (i < Q) ? x : H;
  int off = (i < Q) ? i : i - Q;
  float4 v = ((const float4*)src)[off];
  int node = off >> 5, cg = off & 31;
  uint2 o;
  o.x = (unsigned int)f2bf(v.x) | ((unsigned int)f2bf(v.y) << 16);
  o.y = (unsigned int)f2bf(v.z) | ((unsigned int)f2bf(v.w) << 16);
  *(uint2*)(xH + (size_t)node*256 + ((i < Q) ? 0 : 128) + cg*4) = o;
}

// wtg[m][col][k]: m=0..11 -> gate g=m>>2, t=m&3 in {Wx0,Wx1,Wh0,Wh1}[g] (g=2,t>=2 zero)
//                 m=12,13 -> Wh0[2], Wh1[2] (for the final GEMM)
__global__ void cvt_w(const float* __restrict__ Wx0, const float* __restrict__ Wx1,
                      const float* __restrict__ Wh0, const float* __restrict__ Wh1,
                      unsigned short* __restrict__ wtg){
  int i = blockIdx.x*blockDim.x + threadIdx.x;
  if (i >= 14*16384) return;
  int m = i >> 14;
  int r = i & 16383;
  int col = r >> 7, k = r & 127;
  float v;
  if (m < 12){
    int g = m >> 2, t = m & 3;
    int so = g*16384 + k*128 + col;
    if (t == 0)      v = Wx0[so];
    else if (t == 1) v = Wx1[so];
    else if (t == 2) v = (g < 2) ? Wh0[so] : 0.f;
    else             v = (g < 2) ? Wh1[so] : 0.f;
  } else {
    int so = 2*16384 + k*128 + col;
    v = (m == 12) ? Wh0[so] : Wh1[so];
  }
  wtg[(size_t)m*16384 + col*128 + k] = f2bf(v);
}

// ---------------- prop over interleaved x|H (one 512B read per edge) ----------
__global__ void prop_x2(const int* __restrict__ rowoff, const int* __restrict__ csr_src,
                        const float* __restrict__ csr_norm,
                        const unsigned short* __restrict__ xH,
                        unsigned short* __restrict__ px, unsigned short* __restrict__ pH){
  int node = blockIdx.x*4 + ((int)threadIdx.x >> 6);
  if (node >= N_NODES) return;
  int lane = threadIdx.x & 63;
  int half = lane >> 5, il = lane & 31;
  const unsigned short* base = xH + half*128 + il*4;
  int beg = rowoff[node], end = rowoff[node+1];
  float a0 = 0.f, a1 = 0.f, a2 = 0.f, a3 = 0.f;
  int k = beg;
  for (; k + 8 <= end; k += 8){
    int s[8]; float wn[8]; uint2 v[8];
    #pragma unroll
    for (int u = 0; u < 8; ++u){ s[u] = csr_src[k+u]; wn[u] = csr_norm[k+u]; }
    #pragma unroll
    for (int u = 0; u < 8; ++u) v[u] = *(const uint2*)(base + (size_t)s[u]*256);
    #pragma unroll
    for (int u = 0; u < 8; ++u){
      a0 += wn[u]*bflo(v[u].x); a1 += wn[u]*bfhi(v[u].x);
      a2 += wn[u]*bflo(v[u].y); a3 += wn[u]*bfhi(v[u].y);
    }
  }
  for (; k < end; ++k){
    int s = csr_src[k];
    float w = csr_norm[k];
    uint2 v = *(const uint2*)(base + (size_t)s*256);
    a0 += w*bflo(v.x); a1 += w*bfhi(v.x);
    a2 += w*bflo(v.y); a3 += w*bfhi(v.y);
  }
  uint2 o;
  o.x = (unsigned int)f2bf(a0) | ((unsigned int)f2bf(a1) << 16);
  o.y = (unsigned int)f2bf(a2) | ((unsigned int)f2bf(a3) << 16);
  unsigned short* O = (half ? pH : px) + (size_t)node*CH + il*4;
  *(uint2*)O = o;
}

// ---------------- prop of one matrix (stride-128 input) -----------------------
__global__ void prop_one(const int* __restrict__ rowoff, const int* __restrict__ csr_src,
                         const float* __restrict__ csr_norm,
                         const unsigned short* __restrict__ V,
                         unsigned short* __restrict__ O){
  int node = blockIdx.x*4 + ((int)threadIdx.x >> 6);
  if (node >= N_NODES) return;
  int lane = threadIdx.x & 63;
  const unsigned short* base = V + lane*2;
  int beg = rowoff[node], end = rowoff[node+1];
  float a0 = 0.f, a1 = 0.f;
  int k = beg;
  for (; k + 8 <= end; k += 8){
    int s[8]; float wn[8]; unsigned int v[8];
    #pragma unroll
    for (int u = 0; u < 8; ++u){ s[u] = csr_src[k+u]; wn[u] = csr_norm[k+u]; }
    #pragma unroll
    for (int u = 0; u < 8; ++u) v[u] = *(const unsigned int*)(base + (size_t)s[u]*CH);
    #pragma unroll
    for (int u = 0; u < 8; ++u){
      a0 += wn[u]*bflo(v[u]); a1 += wn[u]*bfhi(v[u]);
    }
  }
  for (; k < end; ++k){
    int s = csr_src[k];
    float w = csr_norm[k];
    unsigned int v = *(const unsigned int*)(base + (size_t)s*CH);
    a0 += w*bflo(v); a1 += w*bfhi(v);
  }
  *(unsigned int*)(O + (size_t)node*CH + lane*2) =
      (unsigned int)f2bf(a0) | ((unsigned int)f2bf(a1) << 16);
}

// ---------------- gate GEMM: B stationary in LDS (staged ONCE, no loop barriers)
// grid (85, 6): flavor = y>>1 (0=Z 1=R 2=P2), colhalf = y&1.
// block 256 = 4 waves x 16 cols. LDS: 4 waves x 16 frags x 1KB = 64 KB.
// Each lane stages its own B fragment (per-lane global src, lane-linear LDS).
// Tile = 64 rows; per B-frag ds_read -> 4 MFMAs.
__launch_bounds__(256)
__global__ void mfma_gatesL(const unsigned short* __restrict__ xH,
                            const unsigned short* __restrict__ px,
                            const unsigned short* __restrict__ pH,
                            const unsigned short* __restrict__ wtg,
                            const float* __restrict__ bx, const float* __restrict__ bh,
                            unsigned short* __restrict__ zb,
                            unsigned short* __restrict__ hrb,
                            float* __restrict__ pre2){
  __shared__ unsigned short Bs[4][16][512];
  const int flavor  = blockIdx.y >> 1;
  const int colhalf = blockIdx.y & 1;
  int lane = threadIdx.x & 63;
  int w    = threadIdx.x >> 6;
  int lr   = lane & 15;
  int kq   = lane >> 4;
  int mycol = colhalf*64 + w*16 + lr;

  const int nfr = (flavor == 2) ? 8 : 16;
  for (int i = 0; i < nfr; ++i){
    int t = i >> 2, q = i & 3;
    const unsigned short* src = wtg + (size_t)(flavor*4 + t)*16384
                              + (size_t)mycol*CH + q*32 + kq*8;
    gload16(src, &Bs[w][i][0]);
  }
  __syncthreads();

  float bs = (flavor == 0) ? bx[mycol] + bh[mycol]
           : (flavor == 1) ? bx[128 + mycol] + bh[128 + mycol]
                           : bx[256 + mycol];

  const unsigned short* Am[4] = {xH, px, xH + 128, pH};
  const int strA[4] = {256, 128, 256, 128};

  for (int tile = blockIdx.x; tile < NT64; tile += gridDim.x){
    int r0 = tile * 64;
    int rA[4];
    #pragma unroll
    for (int rg = 0; rg < 4; ++rg) rA[rg] = min(r0 + rg*16 + lr, N_NODES - 1);
    f32x4 acc[4];
    #pragma unroll
    for (int rg = 0; rg < 4; ++rg) acc[rg] = (f32x4){0.f,0.f,0.f,0.f};

    if (flavor < 2){
      #pragma unroll
      for (int t = 0; t < 4; ++t){
        #pragma unroll
        for (int q = 0; q < 4; ++q){
          bf16x8 b = *(const bf16x8*)&Bs[w][t*4+q][lane*8];
          #pragma unroll
          for (int rg = 0; rg < 4; ++rg){
            bf16x8 a = *(const bf16x8*)(Am[t] + (size_t)rA[rg]*strA[t] + q*32 + kq*8);
            acc[rg] = __builtin_amdgcn_mfma_f32_16x16x32_bf16(a, b, acc[rg], 0, 0, 0);
          }
        }
      }
    } else {
      #pragma unroll
      for (int t = 0; t < 2; ++t){
        #pragma unroll
        for (int q = 0; q < 4; ++q){
          bf16x8 b = *(const bf16x8*)&Bs[w][t*4+q][lane*8];
          #pragma unroll
          for (int rg = 0; rg < 4; ++rg){
            bf16x8 a = *(const bf16x8*)(Am[t] + (size_t)rA[rg]*strA[t] + q*32 + kq*8);
            acc[rg] = __builtin_amdgcn_mfma_f32_16x16x32_bf16(a, b, acc[rg], 0, 0, 0);
          }
        }
      }
    }

    #pragma unroll
    for (int rg = 0; rg < 4; ++rg){
      #pragma unroll
      for (int j = 0; j < 4; ++j){
        int row = r0 + rg*16 + kq*4 + j;
        if (row >= N_NODES) continue;
        size_t o = (size_t)row*CH + mycol;
        float v = acc[rg][j] + bs;
        if (flavor == 0){
          zb[o] = f2bf(1.0f/(1.0f + __expf(-v)));
        } else if (flavor == 1){
          float h = bf2f(xH[(size_t)row*256 + 128 + mycol]);
          hrb[o] = f2bf(h * (1.0f/(1.0f + __expf(-v))));
        } else {
          pre2[o] = v;
        }
      }
    }
  }
}

// ---------------- final GEMM + GRU epilogue: B stationary in LDS --------------
// grid (391, 2): colhalf. block 256 = 4 waves x 16 cols. LDS 32 KB.
__launch_bounds__(256)
__global__ void mfma_finalL(const unsigned short* __restrict__ hr,
                            const unsigned short* __restrict__ phr,
                            const unsigned short* __restrict__ wtg,
                            const float* __restrict__ bh,
                            const float* __restrict__ Hp, const float* __restrict__ pre2,
                            const unsigned short* __restrict__ zb,
                            float* __restrict__ hidden,
                            unsigned short* __restrict__ relu_b){
  __shared__ unsigned short Bs[4][8][512];
  const int colhalf = blockIdx.y;
  int lane = threadIdx.x & 63;
  int w    = threadIdx.x >> 6;
  int lr   = lane & 15;
  int kq   = lane >> 4;
  int mycol = colhalf*64 + w*16 + lr;

  for (int i = 0; i < 8; ++i){
    int t = i >> 2, q = i & 3;
    const unsigned short* src = wtg + (size_t)(12 + t)*16384
                              + (size_t)mycol*CH + q*32 + kq*8;
    gload16(src, &Bs[w][i][0]);
  }
  __syncthreads();

  float bs = bh[256 + mycol];
  const unsigned short* Am[2] = {hr, phr};

  for (int tile = blockIdx.x; tile < NT64; tile += gridDim.x){
    int r0 = tile * 64;
    int rA[4];
    #pragma unroll
    for (int rg = 0; rg < 4; ++rg) rA[rg] = min(r0 + rg*16 + lr, N_NODES - 1);
    f32x4 acc[4];
    #pragma unroll
    for (int rg = 0; rg < 4; ++rg) acc[rg] = (f32x4){0.f,0.f,0.f,0.f};

    #pragma unroll
    for (int t = 0; t < 2; ++t){
      #pragma unroll
      for (int q = 0; q < 4; ++q){
        bf16x8 b = *(const bf16x8*)&Bs[w][t*4+q][lane*8];
        #pragma unroll
        for (int rg = 0; rg < 4; ++rg){
          bf16x8 a = *(const bf16x8*)(Am[t] + (size_t)rA[rg]*CH + q*32 + kq*8);
          acc[rg] = __builtin_amdgcn_mfma_f32_16x16x32_bf16(a, b, acc[rg], 0, 0, 0);
        }
      }
    }

    #pragma unroll
    for (int rg = 0; rg < 4; ++rg){
      #pragma unroll
      for (int j = 0; j < 4; ++j){
        int row = r0 + rg*16 + kq*4 + j;
        if (row >= N_NODES) continue;
        size_t o = (size_t)row*CH + mycol;
        float ht = tanhf(acc[rg][j] + bs + pre2[o]);
        float z  = bf2f(zb[o]);
        float h  = z*Hp[o] + (1.0f - z)*ht;
        hidden[o] = h;
        relu_b[o] = f2bf(fmaxf(h, 0.0f));
      }
    }
  }
}

// ---------------- link-pred scores: 16-lane group per pair, bf16 rows ---------
__global__ void scores_bf16(const int* __restrict__ eli, const unsigned short* __restrict__ hr,
                            const float* __restrict__ pw, const float* __restrict__ pb,
                            float* __restrict__ out){
  __shared__ float sw[CH];
  int t = threadIdx.x;
  if (t < CH) sw[t] = pw[2*t] + pw[2*t + 1];
  __syncthreads();
  int pair = blockIdx.x*16 + (t >> 4);
  if (pair >= N_EL) return;
  int il = t & 15;
  int a = eli[pair];
  int b = eli[N_EL + pair];
  bf16x8 va = *(const bf16x8*)(hr + (size_t)a*CH + il*8);
  bf16x8 vb = *(const bf16x8*)(hr + (size_t)b*CH + il*8);
  float s = 0.f;
  #pragma unroll
  for (int j = 0; j < 8; ++j){
    s += bf2f((unsigned short)va[j]) * bf2f((unsigned short)vb[j]) * sw[il*8 + j];
  }
  s += __shfl_xor(s, 1, 64);
  s += __shfl_xor(s, 2, 64);
  s += __shfl_xor(s, 4, 64);
  s += __shfl_xor(s, 8, 64);
  if (il == 0) out[pair] = s + pb[0] + pb[1];
}

extern "C" void kernel_launch(void* const* d_in, const int* in_sizes, int n_in,
                              void* d_out, int out_size, void* d_ws, size_t ws_size,
                              hipStream_t stream) {
  const float* x   = (const float*)d_in[0];
  const int*   ei  = (const int*)d_in[1];
  const int*   eli = (const int*)d_in[2];
  const float* H   = (const float*)d_in[3];
  const float* Wx0 = (const float*)d_in[4];
  const float* Wx1 = (const float*)d_in[5];
  const float* bx  = (const float*)d_in[6];
  const float* Wh0 = (const float*)d_in[7];
  const float* Wh1 = (const float*)d_in[8];
  const float* bh  = (const float*)d_in[9];
  const float* pw  = (const float*)d_in[10];
  const float* pb  = (const float*)d_in[11];
  float* out    = (float*)d_out;
  float* scores = out;
  float* hidden = out + N_EL;

  char* w = (char*)d_ws;
  auto alloc = [&](size_t b){ void* p = (void*)w; w += (b + 255) & ~(size_t)255; return p; };
  int*   deg      = (int*)  alloc((size_t)N_NODES*4);
  int*   cnt      = (int*)  alloc((size_t)N_NODES*4);
  float* dinv     = (float*)alloc((size_t)N_NODES*4);
  int*   rowoff   = (int*)  alloc((size_t)(N_NODES+1)*4);
  int*   cursor   = (int*)  alloc((size_t)N_NODES*4);
  int*   bsum     = (int*)  alloc((size_t)SCAN_NB*4);
  int*   boff     = (int*)  alloc((size_t)SCAN_NB*4);
  int*   csr_src  = (int*)  alloc((size_t)N_EDGES*4);
  float* csr_norm = (float*)alloc((size_t)N_EDGES*4);
  unsigned short* wtg = (unsigned short*)alloc((size_t)14*16384*2);
  unsigned short* xHb = (unsigned short*)alloc((size_t)N_NODES*256*2);  // x|H interleaved
  unsigned short* pxb = (unsigned short*)alloc((size_t)N_NODES*CH*2);
  unsigned short* pHb = (unsigned short*)alloc((size_t)N_NODES*CH*2);
  unsigned short* zbb = (unsigned short*)alloc((size_t)N_NODES*CH*2);
  unsigned short* hrb = (unsigned short*)alloc((size_t)N_NODES*CH*2);
  float* pre2 = (float*)alloc((size_t)N_NODES*CH*4);
  unsigned short* pHRb   = pHb;   // pHb dead after mfma_gatesL
  unsigned short* relu_b = pxb;   // pxb dead after mfma_gatesL

  hipMemsetAsync(deg, 0, (size_t)N_NODES*4, stream);
  hipMemsetAsync(cnt, 0, (size_t)N_NODES*4, stream);

  hist_kernel<<<(N_EDGES+255)/256, 256, 0, stream>>>(ei, deg, cnt);
  dinv_kernel<<<(N_NODES+255)/256, 256, 0, stream>>>(deg, dinv);
  scan_bsum <<<SCAN_NB, 256, 0, stream>>>(cnt, bsum);
  scan_boff <<<1, 256, 0, stream>>>(bsum, boff);
  scan_final<<<SCAN_NB, 256, 0, stream>>>(cnt, boff, rowoff, cursor);
  scatter_kernel<<<(N_EDGES+255)/256, 256, 0, stream>>>(ei, dinv, cursor, csr_src, csr_norm);

  cvt_xH<<<(((N_NODES*CH)/4)*2 + 255)/256, 256, 0, stream>>>(x, H, xHb);
  cvt_w <<<(14*16384 + 255)/256, 256, 0, stream>>>(Wx0, Wx1, Wh0, Wh1, wtg);

  prop_x2<<<(N_NODES+3)/4, 256, 0, stream>>>(rowoff, csr_src, csr_norm, xHb, pxb, pHb);

  // gates: Z (bf16 zbb), R -> HR (bf16 hrb), P2 (fp32 pre2); grid (85, 3x2)
  mfma_gatesL<<<dim3(85, 6), 256, 0, stream>>>(xHb, pxb, pHb, wtg, bx, bh,
                                               zbb, hrb, pre2);
  // pHR = prop(HR)
  prop_one<<<(N_NODES+3)/4, 256, 0, stream>>>(rowoff, csr_src, csr_norm, hrb, pHRb);
  // gate 2 h-part + GRU finalize: hidden (fp32, d_out) + relu (bf16)
  mfma_finalL<<<dim3(391, 2), 256, 0, stream>>>(hrb, pHRb, wtg, bh,
                                                H, pre2, zbb, hidden, relu_b);

  scores_bf16<<<(N_EL+15)/16, 256, 0, stream>>>(eli, relu_b, pw, pb, scores);
}

// Round 9
// 469.614 us; speedup vs baseline: 1.3214x; 1.2696x over previous
//
#include <hip/hip_runtime.h>

#define N_NODES 50000
#define N_PAD   50048   // 391 * 128
#define N_EDGES 800000
#define N_EL    200000
#define CH      128

typedef __attribute__((ext_vector_type(8))) short bf16x8;
typedef __attribute__((ext_vector_type(4))) float f32x4;

__device__ __forceinline__ unsigned short f2bf(float f){
  unsigned int u = __float_as_uint(f);
  unsigned int r = (u + 0x7fff + ((u >> 16) & 1)) >> 16;
  return (unsigned short)r;
}
__device__ __forceinline__ float bflo(unsigned int v){ return __uint_as_float(v << 16); }
__device__ __forceinline__ float bfhi(unsigned int v){ return __uint_as_float(v & 0xffff0000u); }
__device__ __forceinline__ float bf2f(unsigned short u){ return __uint_as_float(((unsigned int)u) << 16); }

__device__ __forceinline__ void gload16(const void* g, void* l){
  __builtin_amdgcn_global_load_lds(
      (const __attribute__((address_space(1))) unsigned int*)g,
      (__attribute__((address_space(3))) unsigned int*)l, 16, 0, 0);
}

// ---------------- degree histogram --------------------------------------------
__global__ void hist_kernel(const int* __restrict__ ei, int* deg, int* cnt){
  int i = blockIdx.x*blockDim.x + threadIdx.x;
  if (i < N_EDGES){
    atomicAdd(&deg[ei[i]], 1);
    atomicAdd(&cnt[ei[N_EDGES + i]], 1);
  }
}

__global__ void dinv_kernel(const int* __restrict__ deg, float* __restrict__ dinv){
  int i = blockIdx.x*blockDim.x + threadIdx.x;
  if (i < N_NODES){
    int d = deg[i];
    dinv[i] = d > 0 ? rsqrtf((float)d) : 0.0f;
  }
}

// ---------------- hierarchical exclusive scan ---------------------------------
#define SCAN_NB 196   // ceil(50000/256)

__global__ void scan_bsum(const int* __restrict__ cnt, int* __restrict__ bsum){
  __shared__ int sh[256];
  int i = blockIdx.x*256 + threadIdx.x;
  sh[threadIdx.x] = (i < N_NODES) ? cnt[i] : 0;
  __syncthreads();
  for (int off = 128; off >= 1; off >>= 1){
    if ((int)threadIdx.x < off) sh[threadIdx.x] += sh[threadIdx.x + off];
    __syncthreads();
  }
  if (threadIdx.x == 0) bsum[blockIdx.x] = sh[0];
}

__global__ void scan_boff(const int* __restrict__ bsum, int* __restrict__ boff){
  __shared__ int sh[256];
  int t = threadIdx.x;
  int v = (t < SCAN_NB) ? bsum[t] : 0;
  sh[t] = v;
  __syncthreads();
  for (int off = 1; off < 256; off <<= 1){
    int tv = (t >= off) ? sh[t - off] : 0;
    __syncthreads();
    sh[t] += tv;
    __syncthreads();
  }
  if (t < SCAN_NB) boff[t] = sh[t] - v;
}

__global__ void scan_final(const int* __restrict__ cnt, const int* __restrict__ boff,
                           int* __restrict__ rowoff, int* __restrict__ cursor){
  __shared__ int sh[256];
  int t = threadIdx.x;
  int i = blockIdx.x*256 + t;
  int v = (i < N_NODES) ? cnt[i] : 0;
  sh[t] = v;
  __syncthreads();
  for (int off = 1; off < 256; off <<= 1){
    int tv = (t >= off) ? sh[t - off] : 0;
    __syncthreads();
    sh[t] += tv;
    __syncthreads();
  }
  int o = boff[blockIdx.x] + sh[t] - v;
  if (i < N_NODES){ rowoff[i] = o; cursor[i] = o; }
  if (i == N_NODES - 1) rowoff[N_NODES] = N_EDGES;
}

__global__ void scatter_kernel(const int* __restrict__ ei, const float* __restrict__ dinv,
                               int* cursor, int* __restrict__ csr_src,
                               float* __restrict__ csr_norm){
  int i = blockIdx.x*blockDim.x + threadIdx.x;
  if (i < N_EDGES){
    int s = ei[i];
    int d = ei[N_EDGES + i];
    int pos = atomicAdd(&cursor[d], 1);
    csr_src[pos]  = s;
    csr_norm[pos] = -(dinv[s] * dinv[d]);
  }
}

// ---------------- converts ----------------------------------------------------
// A[node][512] = [ x | px | H | pH ] bf16. cvt writes x -> cols 0:128, H -> 256:384.
__global__ void cvt_xH(const float* __restrict__ x, const float* __restrict__ H,
                       unsigned short* __restrict__ A){
  const int Q = (N_NODES*CH)/4;
  int i = blockIdx.x*blockDim.x + threadIdx.x;
  if (i >= 2*Q) return;
  const float* src = (i < Q) ? x : H;
  int off = (i < Q) ? i : i - Q;
  float4 v = ((const float4*)src)[off];
  int node = off >> 5, cg = off & 31;
  uint2 o;
  o.x = (unsigned int)f2bf(v.x) | ((unsigned int)f2bf(v.y) << 16);
  o.y = (unsigned int)f2bf(v.z) | ((unsigned int)f2bf(v.w) << 16);
  *(uint2*)(A + (size_t)node*512 + ((i < Q) ? 0 : 256) + cg*4) = o;
}

// wtb[n=384][k=512]: n-gate g=n>>7, col=n&127; k-block t=k>>7 in {Wx0,Wx1,Wh0,Wh1}
//   (g==2 && t>=2 -> 0). wtf[n=128][k=256]: t in {Wh0[2],Wh1[2]}.
// bias[512]: [bx0+bh0 | bx1+bh1 | bx2 | bh2]
__global__ void cvt_w(const float* __restrict__ Wx0, const float* __restrict__ Wx1,
                      const float* __restrict__ bx,
                      const float* __restrict__ Wh0, const float* __restrict__ Wh1,
                      const float* __restrict__ bh,
                      unsigned short* __restrict__ wtb,
                      unsigned short* __restrict__ wtf,
                      float* __restrict__ bias){
  int i = blockIdx.x*blockDim.x + threadIdx.x;
  if (i < 384*512){
    int n = i >> 9, k = i & 511;
    int g = n >> 7, col = n & 127;
    int t = k >> 7, kk = k & 127;
    float v = 0.f;
    if (g < 2 || t < 2){
      const float* W = (t==0) ? Wx0 : (t==1) ? Wx1 : (t==2) ? Wh0 : Wh1;
      v = W[g*16384 + kk*128 + col];
    }
    wtb[(size_t)n*512 + k] = f2bf(v);
  } else if (i < 384*512 + 128*256){
    int r = i - 384*512;
    int n = r >> 8, k = r & 255;
    int t = k >> 7, kk = k & 127;
    const float* W = t ? Wh1 : Wh0;
    wtf[(size_t)n*256 + k] = f2bf(W[2*16384 + kk*128 + n]);
  } else if (i < 384*512 + 128*256 + 512){
    int c = i - (384*512 + 128*256);
    float v;
    if (c < 256)      v = bx[c] + bh[c];
    else if (c < 384) v = bx[c];
    else              v = bh[c - 128];
    bias[c] = v;
  }
}

// ---------------- prop over A rows: x (cols 0:128) and H (cols 256:384) -------
__global__ void prop_x2(const int* __restrict__ rowoff, const int* __restrict__ csr_src,
                        const float* __restrict__ csr_norm,
                        unsigned short* __restrict__ A){
  int node = blockIdx.x*4 + ((int)threadIdx.x >> 6);
  if (node >= N_NODES) return;
  int lane = threadIdx.x & 63;
  int half = lane >> 5, il = lane & 31;
  const unsigned short* base = A + half*256 + il*4;
  int beg = rowoff[node], end = rowoff[node+1];
  float a0 = 0.f, a1 = 0.f, a2 = 0.f, a3 = 0.f;
  int k = beg;
  for (; k + 8 <= end; k += 8){
    int s[8]; float wn[8]; uint2 v[8];
    #pragma unroll
    for (int u = 0; u < 8; ++u){ s[u] = csr_src[k+u]; wn[u] = csr_norm[k+u]; }
    #pragma unroll
    for (int u = 0; u < 8; ++u) v[u] = *(const uint2*)(base + (size_t)s[u]*512);
    #pragma unroll
    for (int u = 0; u < 8; ++u){
      a0 += wn[u]*bflo(v[u].x); a1 += wn[u]*bfhi(v[u].x);
      a2 += wn[u]*bflo(v[u].y); a3 += wn[u]*bfhi(v[u].y);
    }
  }
  for (; k < end; ++k){
    int s = csr_src[k];
    float w = csr_norm[k];
    uint2 v = *(const uint2*)(base + (size_t)s*512);
    a0 += w*bflo(v.x); a1 += w*bfhi(v.x);
    a2 += w*bflo(v.y); a3 += w*bfhi(v.y);
  }
  uint2 o;
  o.x = (unsigned int)f2bf(a0) | ((unsigned int)f2bf(a1) << 16);
  o.y = (unsigned int)f2bf(a2) | ((unsigned int)f2bf(a3) << 16);
  // px -> cols 128:256 ; pH -> cols 384:512
  *(uint2*)(A + (size_t)node*512 + (half ? 384 : 128) + il*4) = o;
}

// ---------------- prop of HR: A2 cols 0:128 -> A2 cols 128:256 ----------------
__global__ void prop_one(const int* __restrict__ rowoff, const int* __restrict__ csr_src,
                         const float* __restrict__ csr_norm,
                         unsigned short* __restrict__ A2){
  int node = blockIdx.x*4 + ((int)threadIdx.x >> 6);
  if (node >= N_NODES) return;
  int lane = threadIdx.x & 63;
  const unsigned short* base = A2 + lane*2;
  int beg = rowoff[node], end = rowoff[node+1];
  float a0 = 0.f, a1 = 0.f;
  int k = beg;
  for (; k + 8 <= end; k += 8){
    int s[8]; float wn[8]; unsigned int v[8];
    #pragma unroll
    for (int u = 0; u < 8; ++u){ s[u] = csr_src[k+u]; wn[u] = csr_norm[k+u]; }
    #pragma unroll
    for (int u = 0; u < 8; ++u) v[u] = *(const unsigned int*)(base + (size_t)s[u]*256);
    #pragma unroll
    for (int u = 0; u < 8; ++u){
      a0 += wn[u]*bflo(v[u]); a1 += wn[u]*bfhi(v[u]);
    }
  }
  for (; k < end; ++k){
    int s = csr_src[k];
    float w = csr_norm[k];
    unsigned int v = *(const unsigned int*)(base + (size_t)s*256);
    a0 += w*bflo(v); a1 += w*bfhi(v);
  }
  *(unsigned int*)(A2 + (size_t)node*256 + 128 + lane*2) =
      (unsigned int)f2bf(a0) | ((unsigned int)f2bf(a1) << 16);
}

// ---------------- canonical m97-style tile GEMM (BM=BN=128, BK=32, dbuf LDS) --
// 256 thr = 4 waves in 2x2; wave quadrant 64x64; 16 MFMA + 8 ds_read_b128/step.
// A,B staged via global_load_lds (linear dest, inverse-swizzled src, swizzled read).
// GATES=1: grid (391,3), flavor=blockIdx.y: 0 Z->bf16, 1 HR->A2, 2 pre2->f32.
// GATES=0: grid (391,1): final GRU epilogue.
template<int KSTEPS, int KA, int KB, int GATES>
__launch_bounds__(256)
__global__ void gemm_tile(const unsigned short* __restrict__ Ag,
                          const unsigned short* __restrict__ Bg,
                          const float* __restrict__ bias,
                          unsigned short* zb,            // gates: Z out
                          unsigned short* __restrict__ a2hr, // gates: HR out (A2 cols 0:128)
                          float* pre2,                   // gates: out / final: in
                          const float* __restrict__ Hp,  // final: fp32 H
                          float* __restrict__ hidden,    // final: d_out
                          float* __restrict__ relu_unused){
  __shared__ unsigned short Al[2][4096];
  __shared__ unsigned short Bl[2][4096];
  int t = threadIdx.x;
  int lane = t & 63, w = t >> 6;
  int wr = w >> 1, wc = w & 1;
  int lr = lane & 15, kq = lane >> 4;
  int r0 = blockIdx.x * 128;
  int flavor = GATES ? (int)blockIdx.y : 0;
  int n0 = flavor * 128;

  f32x4 acc[4][4];
  #pragma unroll
  for (int i = 0; i < 4; ++i)
    #pragma unroll
    for (int j = 0; j < 4; ++j) acc[i][j] = (f32x4){0.f,0.f,0.f,0.f};

  auto stage = [&](int s, int b){
    #pragma unroll
    for (int p = 0; p < 2; ++p){
      int c = p*256 + w*64 + lane;
      int row = c >> 2, kch = c & 3;
      const unsigned short* src = Ag + (size_t)(r0 + row)*KA + s*32
                                + ((kch ^ (row & 3)) << 3);
      gload16(src, &Al[b][(p*256 + w*64)*8]);
    }
    #pragma unroll
    for (int p = 0; p < 2; ++p){
      int c = p*256 + w*64 + lane;
      int col = c >> 2, kch = c & 3;
      const unsigned short* src = Bg + (size_t)(n0 + col)*KB + s*32
                                + ((kch ^ (col & 3)) << 3);
      gload16(src, &Bl[b][(p*256 + w*64)*8]);
    }
  };

  stage(0, 0);
  __syncthreads();

  const int swzk = (kq ^ (lr & 3)) << 3;
  for (int s = 0; s < KSTEPS; ++s){
    int b = s & 1;
    if (s + 1 < KSTEPS) stage(s + 1, b ^ 1);
    bf16x8 af[4], bfr[4];
    #pragma unroll
    for (int i = 0; i < 4; ++i)
      af[i] = *(const bf16x8*)&Al[b][(wr*64 + i*16 + lr)*32 + swzk];
    #pragma unroll
    for (int j = 0; j < 4; ++j)
      bfr[j] = *(const bf16x8*)&Bl[b][(wc*64 + j*16 + lr)*32 + swzk];
    #pragma unroll
    for (int i = 0; i < 4; ++i)
      #pragma unroll
      for (int j = 0; j < 4; ++j)
        acc[i][j] = __builtin_amdgcn_mfma_f32_16x16x32_bf16(af[i], bfr[j], acc[i][j], 0, 0, 0);
    __syncthreads();
  }

  float bs[4];
  #pragma unroll
  for (int j = 0; j < 4; ++j)
    bs[j] = bias[(GATES ? flavor*128 : 384) + wc*64 + j*16 + lr];

  #pragma unroll
  for (int i = 0; i < 4; ++i){
    #pragma unroll
    for (int j = 0; j < 4; ++j){
      int col = wc*64 + j*16 + lr;
      #pragma unroll
      for (int g = 0; g < 4; ++g){
        int row = r0 + wr*64 + i*16 + kq*4 + g;
        if (row >= N_NODES) continue;
        size_t o = (size_t)row*CH + col;
        float v = acc[i][j][g] + bs[j];
        if (GATES){
          if (flavor == 0){
            zb[o] = f2bf(1.0f/(1.0f + __expf(-v)));
          } else if (flavor == 1){
            float h = bf2f(Ag[(size_t)row*512 + 256 + col]);
            a2hr[(size_t)row*256 + col] = f2bf(h * (1.0f/(1.0f + __expf(-v))));
          } else {
            pre2[o] = v;
          }
        } else {
          float ht = tanhf(v + pre2[o]);
          float z  = bf2f(zb[o]);
          float h  = z*Hp[o] + (1.0f - z)*ht;
          hidden[o] = h;
        }
      }
    }
  }
}

// ---------------- link-pred scores from fp32 hidden (relu applied inline) -----
__global__ void scores_f32(const int* __restrict__ eli, const float* __restrict__ hid,
                           const float* __restrict__ pw, const float* __restrict__ pb,
                           float* __restrict__ out){
  __shared__ float sw[CH];
  int t = threadIdx.x;
  if (t < CH) sw[t] = pw[2*t] + pw[2*t + 1];
  __syncthreads();
  int pair = blockIdx.x*16 + (t >> 4);
  if (pair >= N_EL) return;
  int il = t & 15;
  int a = eli[pair];
  int b = eli[N_EL + pair];
  const float* ra = hid + (size_t)a*CH;
  const float* rb = hid + (size_t)b*CH;
  float4 va0 = *(const float4*)(ra + il*4);
  float4 vb0 = *(const float4*)(rb + il*4);
  float4 va1 = *(const float4*)(ra + 64 + il*4);
  float4 vb1 = *(const float4*)(rb + 64 + il*4);
  float s = 0.f;
  s += fmaxf(va0.x,0.f)*fmaxf(vb0.x,0.f)*sw[il*4+0];
  s += fmaxf(va0.y,0.f)*fmaxf(vb0.y,0.f)*sw[il*4+1];
  s += fmaxf(va0.z,0.f)*fmaxf(vb0.z,0.f)*sw[il*4+2];
  s += fmaxf(va0.w,0.f)*fmaxf(vb0.w,0.f)*sw[il*4+3];
  s += fmaxf(va1.x,0.f)*fmaxf(vb1.x,0.f)*sw[64+il*4+0];
  s += fmaxf(va1.y,0.f)*fmaxf(vb1.y,0.f)*sw[64+il*4+1];
  s += fmaxf(va1.z,0.f)*fmaxf(vb1.z,0.f)*sw[64+il*4+2];
  s += fmaxf(va1.w,0.f)*fmaxf(vb1.w,0.f)*sw[64+il*4+3];
  s += __shfl_xor(s, 1, 64);
  s += __shfl_xor(s, 2, 64);
  s += __shfl_xor(s, 4, 64);
  s += __shfl_xor(s, 8, 64);
  if (il == 0) out[pair] = s + pb[0] + pb[1];
}

extern "C" void kernel_launch(void* const* d_in, const int* in_sizes, int n_in,
                              void* d_out, int out_size, void* d_ws, size_t ws_size,
                              hipStream_t stream) {
  const float* x   = (const float*)d_in[0];
  const int*   ei  = (const int*)d_in[1];
  const int*   eli = (const int*)d_in[2];
  const float* H   = (const float*)d_in[3];
  const float* Wx0 = (const float*)d_in[4];
  const float* Wx1 = (const float*)d_in[5];
  const float* bx  = (const float*)d_in[6];
  const float* Wh0 = (const float*)d_in[7];
  const float* Wh1 = (const float*)d_in[8];
  const float* bh  = (const float*)d_in[9];
  const float* pw  = (const float*)d_in[10];
  const float* pb  = (const float*)d_in[11];
  float* out    = (float*)d_out;
  float* scores = out;
  float* hidden = out + N_EL;

  char* w = (char*)d_ws;
  auto alloc = [&](size_t b){ void* p = (void*)w; w += (b + 255) & ~(size_t)255; return p; };
  int*   deg      = (int*)  alloc((size_t)N_NODES*4);
  int*   cnt      = (int*)  alloc((size_t)N_NODES*4);
  float* dinv     = (float*)alloc((size_t)N_NODES*4);
  int*   rowoff   = (int*)  alloc((size_t)(N_NODES+1)*4);
  int*   cursor   = (int*)  alloc((size_t)N_NODES*4);
  int*   bsum     = (int*)  alloc((size_t)SCAN_NB*4);
  int*   boff     = (int*)  alloc((size_t)SCAN_NB*4);
  int*   csr_src  = (int*)  alloc((size_t)N_EDGES*4);
  float* csr_norm = (float*)alloc((size_t)N_EDGES*4);
  unsigned short* wtb  = (unsigned short*)alloc((size_t)384*512*2);
  unsigned short* wtf  = (unsigned short*)alloc((size_t)128*256*2);
  float*          bias = (float*)alloc((size_t)512*4);
  unsigned short* Abuf = (unsigned short*)alloc((size_t)N_PAD*512*2);  // [x|px|H|pH]
  unsigned short* A2   = (unsigned short*)alloc((size_t)N_PAD*256*2);  // [hr|phr]
  unsigned short* zbb  = (unsigned short*)alloc((size_t)N_PAD*CH*2);
  float*          pre2 = (float*)alloc((size_t)N_PAD*CH*4);

  hipMemsetAsync(deg, 0, (size_t)N_NODES*4, stream);
  hipMemsetAsync(cnt, 0, (size_t)N_NODES*4, stream);

  hist_kernel<<<(N_EDGES+255)/256, 256, 0, stream>>>(ei, deg, cnt);
  dinv_kernel<<<(N_NODES+255)/256, 256, 0, stream>>>(deg, dinv);
  scan_bsum <<<SCAN_NB, 256, 0, stream>>>(cnt, bsum);
  scan_boff <<<1, 256, 0, stream>>>(bsum, boff);
  scan_final<<<SCAN_NB, 256, 0, stream>>>(cnt, boff, rowoff, cursor);
  scatter_kernel<<<(N_EDGES+255)/256, 256, 0, stream>>>(ei, dinv, cursor, csr_src, csr_norm);

  cvt_xH<<<(((N_NODES*CH)/4)*2 + 255)/256, 256, 0, stream>>>(x, H, Abuf);
  cvt_w <<<(384*512 + 128*256 + 512 + 255)/256, 256, 0, stream>>>(Wx0, Wx1, bx, Wh0, Wh1, bh,
                                                                  wtb, wtf, bias);

  prop_x2<<<(N_NODES+3)/4, 256, 0, stream>>>(rowoff, csr_src, csr_norm, Abuf);

  // fused gate GEMM: C[50048,384] = A[50048,512] @ wtb[512,384]
  gemm_tile<16, 512, 512, 1><<<dim3(391, 3), 256, 0, stream>>>(
      Abuf, wtb, bias, zbb, A2, pre2, nullptr, nullptr, nullptr);

  // pHR = prop(HR): A2 cols 0:128 -> 128:256
  prop_one<<<(N_NODES+3)/4, 256, 0, stream>>>(rowoff, csr_src, csr_norm, A2);

  // final GEMM + GRU epilogue -> hidden (d_out)
  gemm_tile<8, 256, 256, 0><<<dim3(391, 1), 256, 0, stream>>>(
      A2, wtf, bias, zbb, nullptr, pre2, H, hidden, nullptr);

  scores_f32<<<(N_EL+15)/16, 256, 0, stream>>>(eli, hidden, pw, pb, scores);
}